// Round 19
// baseline (31.094 us; speedup 1.0000x reference)
//
#include <hip/hip_runtime.h>
#include <math.h>

#define NB 16
#define NL 64
#define NK 32
#define NC 32
#define ND 512
#define EPSF 1e-10f

#define TILES_PER_B 36
#define PAIR_BLOCKS (NB * TILES_PER_B * 4)   // 2304 quarter-tile blocks

// att iff jsd < 5  <=>  stat = H2_i + H2_j + 64 - S < 10/ln2
#define THRS 14.426950408889634f
#define L2E  1.4426950408889634f

typedef _Float16 half2v __attribute__((ext_vector_type(2)));
typedef _Float16 half4v __attribute__((ext_vector_type(4)));
typedef _Float16 half8v __attribute__((ext_vector_type(8)));

// ws layout (floats):
//   partials : PAIR_BLOCKS*4 = 9216 floats at offset 0
//   midc     : 32 ints at float offset 9216
//   root     : 1 int  at float offset 9248
//   P  (f16) : 1,048,576 halves (2 MB) at float offset 16384
//   H2 (f32) : 1024 floats after P
//   h16(f16) : 524,288 halves (1 MB) after H2

__global__ void __launch_bounds__(256) softmax_kernel(
        const float* __restrict__ prior,
        const float* __restrict__ hg,
        _Float16* __restrict__ P,
        float* __restrict__ H2,
        _Float16* __restrict__ h16,
        int* __restrict__ counters) {   // midc[32] + root
    int bl = blockIdx.x;
    int t  = threadIdx.x;
    if (bl == 0 && t < 33)
        __hip_atomic_store(&counters[t], 0, __ATOMIC_RELAXED,
                           __HIP_MEMORY_SCOPE_AGENT);

    const float* src = prior + (size_t)bl * (NK * NC);
    float4 x = *(const float4*)(src + t * 4);
    float y0 = x.x * L2E, y1 = x.y * L2E, y2 = x.z * L2E, y3 = x.w * L2E;

    float m = fmaxf(fmaxf(y0, y1), fmaxf(y2, y3));
    #pragma unroll
    for (int w = 4; w >= 1; w >>= 1)
        m = fmaxf(m, __shfl_xor(m, w, 8));      // 8 lanes per k-row

    float e0 = exp2f(y0 - m), e1 = exp2f(y1 - m);
    float e2 = exp2f(y2 - m), e3 = exp2f(y3 - m);
    float s = e0 + e1 + e2 + e3;
    #pragma unroll
    for (int w = 4; w >= 1; w >>= 1)
        s += __shfl_xor(s, w, 8);

    float rs = 1.0f / s;
    float ls = __log2f(s);
    float p0 = e0 * rs, p1 = e1 * rs, p2 = e2 * rs, p3 = e3 * rs;
    float l0 = (y0 - m) - ls, l1 = (y1 - m) - ls;
    float l2 = (y2 - m) - ls, l3 = (y3 - m) - ls;

    half4v pv;
    pv[0] = (_Float16)fmaxf(p0, 1e-6f);
    pv[1] = (_Float16)fmaxf(p1, 1e-6f);
    pv[2] = (_Float16)fmaxf(p2, 1e-6f);
    pv[3] = (_Float16)fmaxf(p3, 1e-6f);
    *(half4v*)(P + (size_t)bl * (NK * NC) + t * 4) = pv;

    float2 hv = *(const float2*)(hg + (size_t)bl * ND + t * 2);
    half2v hh; hh[0] = (_Float16)hv.x; hh[1] = (_Float16)hv.y;
    *(half2v*)(h16 + (size_t)bl * ND + t * 2) = hh;

    float hacc = p0 * l0 + p1 * l1 + p2 * l2 + p3 * l3;
    #pragma unroll
    for (int w = 32; w >= 1; w >>= 1)
        hacc += __shfl_xor(hacc, w);
    __shared__ float red[4];
    int lane = t & 63, wib = t >> 6;
    if (lane == 0) red[wib] = hacc;
    __syncthreads();
    if (t == 0) H2[bl] = red[0] + red[1] + red[2] + red[3];
}

// DPP funnel add (row_shr:N, bound_ctrl) — reduce-to-LAST-lane of 16-row.
template<int CTRL>
__device__ __forceinline__ float dpp_add(float x) {
    int yi = __builtin_amdgcn_update_dpp(0, __float_as_int(x), CTRL, 0xF, 0xF, true);
    return x + __int_as_float(yi);
}

// 4-value reduce: value q's full sum lands on lane 16q+15.
__device__ __forceinline__ float bf4f(float v0, float v1, float v2, float v3,
                                      bool hi32, bool hi16) {
    float sel0 = hi32 ? v2 : v0, oth0 = hi32 ? v0 : v2;
    float sel1 = hi32 ? v3 : v1, oth1 = hi32 ? v1 : v3;
    float w0 = sel0 + __shfl_xor(oth0, 32);
    float w1 = sel1 + __shfl_xor(oth1, 32);
    float sel = hi16 ? w1 : w0, oth = hi16 ? w0 : w1;
    float x = sel + __shfl_xor(oth, 16);
    x = dpp_add<0x111>(x);   // row_shr:1
    x = dpp_add<0x112>(x);   // row_shr:2
    x = dpp_add<0x114>(x);   // row_shr:4
    x = dpp_add<0x118>(x);   // row_shr:8
    return x;                // full sum valid on lanes with (lane&15)==15
}

// 2304 blocks x 256 threads (4 waves), XCD-bijective swizzle (each XCD gets
// 288 consecutive quarter-tiles = 2 whole batches -> per-XCD L2 working set
// ~400 KB). R17 hot loop. Completion: sc1 partial stores (no serialization)
// + 32-way mid-counter tree + root; global-last block reduces and writes out.
__global__ void __launch_bounds__(256) pair_kernel(
        const _Float16* __restrict__ P,
        const float* __restrict__ H2g,
        const _Float16* __restrict__ h16,
        float* __restrict__ partials,
        int* __restrict__ counters,      // midc[32] + root at [32]
        float* __restrict__ out) {
    __shared__ float red[4][4];
    __shared__ int lastFlag;

    int tid  = threadIdx.x;
    int lane = tid & 63;
    int wv   = tid >> 6;

    // XCD-bijective swizzle: 2304 = 8 * 288
    int wg = (blockIdx.x & 7) * 288 + (blockIdx.x >> 3);

    int b      = wg / (TILES_PER_B * 4);
    int rem144 = wg % (TILES_PER_B * 4);
    int t36    = rem144 >> 2;
    int quad   = rem144 & 3;

    int ti = 0, rem = t36;
    while (rem >= 8 - ti) { rem -= 8 - ti; ++ti; }
    int tj = ti + rem;
    bool diag = (ti == tj);
    int bi0 = b * NL + ti * 8;
    int bj0 = b * NL + tj * 8;

    int r    = quad * 2 + (wv >> 1);     // row within tile, 0..7
    int scol = (wv & 1) * 4;             // column group: 0..3 or 4..7

    // i-row slice straight into registers (16 halves = 32B per lane)
    const _Float16* arow = P + (size_t)(bi0 + r) * (NK * NC) + lane * 16;
    half8v arA = *(const half8v*)(arow);
    half8v arB = *(const half8v*)(arow + 8);
    half8v hr  = *(const half8v*)(h16 + (size_t)(bi0 + r) * ND + lane * 8);
    float h2i = H2g[bi0 + r];

    const _Float16* Pj = P   + (size_t)bj0 * (NK * NC) + lane * 16;
    const _Float16* Hj = h16 + (size_t)bj0 * ND + lane * 8;

    bool hi32 = (lane & 32) != 0;
    bool hi16 = (lane & 16) != 0;
    int  sgrp = lane >> 4;               // 0..3
    bool actl = (lane & 15) == 15;       // funnel target lanes

    float S[4], M[4];
    #pragma unroll
    for (int q = 0; q < 4; ++q) {
        int s = scol + q;
        const _Float16* brow = Pj + s * 1024;
        half8v b0 = *(const half8v*)(brow);
        half8v b1 = *(const half8v*)(brow + 8);
        half8v t0 = arA + b0;
        half8v t1 = arB + b1;
        float a0 = 0.f, a1 = 0.f, a2 = 0.f, a3 = 0.f;
        #pragma unroll
        for (int e = 0; e < 8; e += 2) {
            float f0 = (float)t0[e];     a0 = fmaf(f0, __log2f(f0), a0);
            float f1 = (float)t0[e + 1]; a1 = fmaf(f1, __log2f(f1), a1);
            float g0 = (float)t1[e];     a2 = fmaf(g0, __log2f(g0), a2);
            float g1 = (float)t1[e + 1]; a3 = fmaf(g1, __log2f(g1), a3);
        }
        S[q] = (a0 + a1) + (a2 + a3);

        half8v hs = *(const half8v*)(Hj + s * 512);
        half8v d = hr - hs;
        float m0 = 0.f, m1 = 0.f;
        #pragma unroll
        for (int e = 0; e < 8; e += 2) {
            m0 = fmaf((float)d[e],     (float)d[e],     m0);
            m1 = fmaf((float)d[e + 1], (float)d[e + 1], m1);
        }
        M[q] = m0 + m1;
    }

    float xS = bf4f(S[0], S[1], S[2], S[3], hi32, hi16);
    float xM = bf4f(M[0], M[1], M[2], M[3], hi32, hi16);

    int s = scol + sgrp;
    float stat = h2i + H2g[bj0 + s] + 64.0f - xS;
    float mse  = xM * (1.0f / ND);
    float rt   = exp2f(-mse * L2E);
    bool valid = (!diag) || (s > r);
    bool isAtt = stat < THRS;

    float attN = (actl && valid && isAtt)  ? mse : 0.f;
    float attC = (actl && valid && isAtt)  ? 1.f : 0.f;
    float repN = (actl && valid && !isAtt) ? rt  : 0.f;
    float repC = (actl && valid && !isAtt) ? 1.f : 0.f;

    attN += __shfl_xor(attN, 16); attN += __shfl_xor(attN, 32);
    attC += __shfl_xor(attC, 16); attC += __shfl_xor(attC, 32);
    repN += __shfl_xor(repN, 16); repN += __shfl_xor(repN, 32);
    repC += __shfl_xor(repC, 16); repC += __shfl_xor(repC, 32);

    if (lane == 63) {
        red[wv][0] = attN; red[wv][1] = attC;
        red[wv][2] = repN; red[wv][3] = repC;
    }
    __syncthreads();
    if (tid < 4) {
        float v = red[0][tid] + red[1][tid] + red[2][tid] + red[3][tid];
        __hip_atomic_store(&partials[blockIdx.x * 4 + tid], v,
                           __ATOMIC_RELAXED, __HIP_MEMORY_SCOPE_AGENT);
    }
    __syncthreads();   // drains vmcnt: sc1 stores are at the coherence point

    if (tid == 0) {
        int g = blockIdx.x & 31;
        int old = __hip_atomic_fetch_add(&counters[g], 1, __ATOMIC_RELAXED,
                                         __HIP_MEMORY_SCOPE_AGENT);
        int lf = 0;
        if (old == (PAIR_BLOCKS / 32) - 1) {           // last in group (72)
            int o2 = __hip_atomic_fetch_add(&counters[32], 1, __ATOMIC_RELAXED,
                                            __HIP_MEMORY_SCOPE_AGENT);
            lf = (o2 == 31);                           // global last
        }
        lastFlag = lf;
    }
    __syncthreads();
    if (!lastFlag) return;

    // ---- global-last block: reduce all partials, write the two losses ----
    float a0 = 0.f, a1 = 0.f, a2 = 0.f, a3 = 0.f;
    for (int bkt = tid; bkt < PAIR_BLOCKS; bkt += 256) {
        a0 += __hip_atomic_load(&partials[bkt * 4 + 0], __ATOMIC_RELAXED, __HIP_MEMORY_SCOPE_AGENT);
        a1 += __hip_atomic_load(&partials[bkt * 4 + 1], __ATOMIC_RELAXED, __HIP_MEMORY_SCOPE_AGENT);
        a2 += __hip_atomic_load(&partials[bkt * 4 + 2], __ATOMIC_RELAXED, __HIP_MEMORY_SCOPE_AGENT);
        a3 += __hip_atomic_load(&partials[bkt * 4 + 3], __ATOMIC_RELAXED, __HIP_MEMORY_SCOPE_AGENT);
    }
    #pragma unroll
    for (int w = 32; w >= 1; w >>= 1) {
        a0 += __shfl_xor(a0, w);
        a1 += __shfl_xor(a1, w);
        a2 += __shfl_xor(a2, w);
        a3 += __shfl_xor(a3, w);
    }
    if (lane == 0) {
        red[wv][0] = a0; red[wv][1] = a1;
        red[wv][2] = a2; red[wv][3] = a3;
    }
    __syncthreads();
    if (tid == 0) {
        float s0 = red[0][0] + red[1][0] + red[2][0] + red[3][0];
        float s1 = red[0][1] + red[1][1] + red[2][1] + red[3][1];
        float s2 = red[0][2] + red[1][2] + red[2][2] + red[3][2];
        float s3 = red[0][3] + red[1][3] + red[2][3] + red[3][3];
        float la = s0 / (s1 + EPSF);
        float lr = s2 / (s3 + EPSF);
        out[0] = (la > 0.0f) ? la : 0.0f;
        out[1] = (lr > 0.0f) ? lr : 0.0f;
    }
}

extern "C" void kernel_launch(void* const* d_in, const int* in_sizes, int n_in,
                              void* d_out, int out_size, void* d_ws, size_t ws_size,
                              hipStream_t stream) {
    const float* prior = (const float*)d_in[0];
    const float* h     = (const float*)d_in[1];
    float* out = (float*)d_out;
    float* ws  = (float*)d_ws;

    float* partials = ws;                                     // 9216 floats
    int*   counters = (int*)(ws + 9216);                      // midc[32]+root
    _Float16* P = (_Float16*)(ws + 16384);                    // 1,048,576 halves
    float* H2 = ws + 16384 + 524288;                          // 1024 floats
    _Float16* h16 = (_Float16*)(ws + 16384 + 524288 + 1024);  // 524,288 halves

    softmax_kernel<<<NB * NL, 256, 0, stream>>>(prior, h, P, H2, h16, counters);

    pair_kernel<<<PAIR_BLOCKS, 256, 0, stream>>>(P, H2, h16, partials, counters, out);
}

// Round 20
// 28.858 us; speedup vs baseline: 1.0775x; 1.0775x over previous
//
#include <hip/hip_runtime.h>
#include <math.h>

#define NB 16
#define NL 64
#define NK 32
#define NC 32
#define ND 512
#define EPSF 1e-10f

#define TILES_PER_B 36
#define PAIR_BLOCKS (NB * TILES_PER_B * 4)   // 2304 quarter-tile blocks

// att iff jsd < 5  <=>  stat = H2_i + H2_j + 64 - S < 10/ln2
#define THRS 14.426950408889634f
#define L2E  1.4426950408889634f

typedef _Float16 half2v __attribute__((ext_vector_type(2)));
typedef _Float16 half4v __attribute__((ext_vector_type(4)));
typedef _Float16 half8v __attribute__((ext_vector_type(8)));

// ws layout (floats):
//   bins     : 256 floats at offset 0 (4 accumulators x 64 spread bins)
//   P  (f16) : 1,048,576 halves (2 MB) at float offset 16384
//   H2 (f32) : 1024 floats after P
//   h16(f16) : 524,288 halves (1 MB) after H2

__global__ void __launch_bounds__(256) softmax_kernel(
        const float* __restrict__ prior,
        const float* __restrict__ hg,
        _Float16* __restrict__ P,
        float* __restrict__ H2,
        _Float16* __restrict__ h16,
        float* __restrict__ bins) {
    int bl = blockIdx.x;
    int t  = threadIdx.x;
    if (bl == 0) bins[t] = 0.0f;   // zero the 256 bins each launch

    const float* src = prior + (size_t)bl * (NK * NC);
    float4 x = *(const float4*)(src + t * 4);
    float y0 = x.x * L2E, y1 = x.y * L2E, y2 = x.z * L2E, y3 = x.w * L2E;

    float m = fmaxf(fmaxf(y0, y1), fmaxf(y2, y3));
    #pragma unroll
    for (int w = 4; w >= 1; w >>= 1)
        m = fmaxf(m, __shfl_xor(m, w, 8));      // 8 lanes per k-row

    float e0 = exp2f(y0 - m), e1 = exp2f(y1 - m);
    float e2 = exp2f(y2 - m), e3 = exp2f(y3 - m);
    float s = e0 + e1 + e2 + e3;
    #pragma unroll
    for (int w = 4; w >= 1; w >>= 1)
        s += __shfl_xor(s, w, 8);

    float rs = 1.0f / s;
    float ls = __log2f(s);
    float p0 = e0 * rs, p1 = e1 * rs, p2 = e2 * rs, p3 = e3 * rs;
    float l0 = (y0 - m) - ls, l1 = (y1 - m) - ls;
    float l2 = (y2 - m) - ls, l3 = (y3 - m) - ls;

    half4v pv;
    pv[0] = (_Float16)fmaxf(p0, 1e-6f);
    pv[1] = (_Float16)fmaxf(p1, 1e-6f);
    pv[2] = (_Float16)fmaxf(p2, 1e-6f);
    pv[3] = (_Float16)fmaxf(p3, 1e-6f);
    *(half4v*)(P + (size_t)bl * (NK * NC) + t * 4) = pv;

    float2 hv = *(const float2*)(hg + (size_t)bl * ND + t * 2);
    half2v hh; hh[0] = (_Float16)hv.x; hh[1] = (_Float16)hv.y;
    *(half2v*)(h16 + (size_t)bl * ND + t * 2) = hh;

    float hacc = p0 * l0 + p1 * l1 + p2 * l2 + p3 * l3;
    #pragma unroll
    for (int w = 32; w >= 1; w >>= 1)
        hacc += __shfl_xor(hacc, w);
    __shared__ float red[4];
    int lane = t & 63, wib = t >> 6;
    if (lane == 0) red[wib] = hacc;
    __syncthreads();
    if (t == 0) H2[bl] = red[0] + red[1] + red[2] + red[3];
}

// DPP funnel add (row_shr:N, bound_ctrl) — reduce-to-LAST-lane of 16-row.
template<int CTRL>
__device__ __forceinline__ float dpp_add(float x) {
    int yi = __builtin_amdgcn_update_dpp(0, __float_as_int(x), CTRL, 0xF, 0xF, true);
    return x + __int_as_float(yi);
}

// 4-value reduce: value q's full sum lands on lane 16q+15.
__device__ __forceinline__ float bf4f(float v0, float v1, float v2, float v3,
                                      bool hi32, bool hi16) {
    float sel0 = hi32 ? v2 : v0, oth0 = hi32 ? v0 : v2;
    float sel1 = hi32 ? v3 : v1, oth1 = hi32 ? v1 : v3;
    float w0 = sel0 + __shfl_xor(oth0, 32);
    float w1 = sel1 + __shfl_xor(oth1, 32);
    float sel = hi16 ? w1 : w0, oth = hi16 ? w0 : w1;
    float x = sel + __shfl_xor(oth, 16);
    x = dpp_add<0x111>(x);   // row_shr:1
    x = dpp_add<0x112>(x);   // row_shr:2
    x = dpp_add<0x114>(x);   // row_shr:4
    x = dpp_add<0x118>(x);   // row_shr:8
    return x;                // full sum valid on lanes with (lane&15)==15
}

// 2304 blocks x 256 threads (4 waves). XCD-bijective swizzle: each XCD gets
// 288 consecutive quarter-tiles (2 whole batches) -> per-XCD L2 working set
// ~400 KB. R17 hot loop (single unconditional pass, pure ILP). Partials go
// to 256 spread atomic bins (36 adds/bin, negligible contention).
__global__ void __launch_bounds__(256) pair_kernel(
        const _Float16* __restrict__ P,
        const float* __restrict__ H2g,
        const _Float16* __restrict__ h16,
        float* __restrict__ bins) {
    __shared__ float red[4][4];

    int tid  = threadIdx.x;
    int lane = tid & 63;
    int wv   = tid >> 6;

    // XCD-bijective swizzle: 2304 = 8 * 288
    int wg = (blockIdx.x & 7) * 288 + (blockIdx.x >> 3);

    int b      = wg / (TILES_PER_B * 4);
    int rem144 = wg % (TILES_PER_B * 4);
    int t36    = rem144 >> 2;
    int quad   = rem144 & 3;

    int ti = 0, rem = t36;
    while (rem >= 8 - ti) { rem -= 8 - ti; ++ti; }
    int tj = ti + rem;
    bool diag = (ti == tj);
    int bi0 = b * NL + ti * 8;
    int bj0 = b * NL + tj * 8;

    int r    = quad * 2 + (wv >> 1);     // row within tile, 0..7
    int scol = (wv & 1) * 4;             // column group: 0..3 or 4..7

    // i-row slice straight into registers (16 halves = 32B per lane)
    const _Float16* arow = P + (size_t)(bi0 + r) * (NK * NC) + lane * 16;
    half8v arA = *(const half8v*)(arow);
    half8v arB = *(const half8v*)(arow + 8);
    half8v hr  = *(const half8v*)(h16 + (size_t)(bi0 + r) * ND + lane * 8);
    float h2i = H2g[bi0 + r];

    const _Float16* Pj = P   + (size_t)bj0 * (NK * NC) + lane * 16;
    const _Float16* Hj = h16 + (size_t)bj0 * ND + lane * 8;

    bool hi32 = (lane & 32) != 0;
    bool hi16 = (lane & 16) != 0;
    int  sgrp = lane >> 4;               // 0..3
    bool actl = (lane & 15) == 15;       // funnel target lanes

    float S[4], M[4];
    #pragma unroll
    for (int q = 0; q < 4; ++q) {
        int s = scol + q;
        const _Float16* brow = Pj + s * 1024;
        half8v b0 = *(const half8v*)(brow);
        half8v b1 = *(const half8v*)(brow + 8);
        half8v t0 = arA + b0;
        half8v t1 = arB + b1;
        float a0 = 0.f, a1 = 0.f, a2 = 0.f, a3 = 0.f;
        #pragma unroll
        for (int e = 0; e < 8; e += 2) {
            float f0 = (float)t0[e];     a0 = fmaf(f0, __log2f(f0), a0);
            float f1 = (float)t0[e + 1]; a1 = fmaf(f1, __log2f(f1), a1);
            float g0 = (float)t1[e];     a2 = fmaf(g0, __log2f(g0), a2);
            float g1 = (float)t1[e + 1]; a3 = fmaf(g1, __log2f(g1), a3);
        }
        S[q] = (a0 + a1) + (a2 + a3);

        half8v hs = *(const half8v*)(Hj + s * 512);
        half8v d = hr - hs;
        float m0 = 0.f, m1 = 0.f;
        #pragma unroll
        for (int e = 0; e < 8; e += 2) {
            m0 = fmaf((float)d[e],     (float)d[e],     m0);
            m1 = fmaf((float)d[e + 1], (float)d[e + 1], m1);
        }
        M[q] = m0 + m1;
    }

    float xS = bf4f(S[0], S[1], S[2], S[3], hi32, hi16);
    float xM = bf4f(M[0], M[1], M[2], M[3], hi32, hi16);

    int s = scol + sgrp;
    float stat = h2i + H2g[bj0 + s] + 64.0f - xS;
    float mse  = xM * (1.0f / ND);
    float rt   = exp2f(-mse * L2E);
    bool valid = (!diag) || (s > r);
    bool isAtt = stat < THRS;

    float attN = (actl && valid && isAtt)  ? mse : 0.f;
    float attC = (actl && valid && isAtt)  ? 1.f : 0.f;
    float repN = (actl && valid && !isAtt) ? rt  : 0.f;
    float repC = (actl && valid && !isAtt) ? 1.f : 0.f;

    attN += __shfl_xor(attN, 16); attN += __shfl_xor(attN, 32);
    attC += __shfl_xor(attC, 16); attC += __shfl_xor(attC, 32);
    repN += __shfl_xor(repN, 16); repN += __shfl_xor(repN, 32);
    repC += __shfl_xor(repC, 16); repC += __shfl_xor(repC, 32);

    if (lane == 63) {
        red[wv][0] = attN; red[wv][1] = attC;
        red[wv][2] = repN; red[wv][3] = repC;
    }
    __syncthreads();
    if (tid < 4) {
        float v = red[0][tid] + red[1][tid] + red[2][tid] + red[3][tid];
        atomicAdd(&bins[tid * 64 + (blockIdx.x & 63)], v);
    }
}

// One block, 256 threads: wave a reduces bins[a*64 .. a*64+63].
__global__ void __launch_bounds__(256) finalize_kernel(
        const float* __restrict__ bins,
        float* __restrict__ out) {
    int tid  = threadIdx.x;
    int lane = tid & 63;
    int wv   = tid >> 6;
    float v = bins[tid];
    #pragma unroll
    for (int w = 32; w >= 1; w >>= 1)
        v += __shfl_xor(v, w);
    __shared__ float red[4];
    if (lane == 0) red[wv] = v;
    __syncthreads();
    if (tid == 0) {
        float la = red[0] / (red[1] + EPSF);
        float lr = red[2] / (red[3] + EPSF);
        out[0] = (la > 0.0f) ? la : 0.0f;
        out[1] = (lr > 0.0f) ? lr : 0.0f;
    }
}

extern "C" void kernel_launch(void* const* d_in, const int* in_sizes, int n_in,
                              void* d_out, int out_size, void* d_ws, size_t ws_size,
                              hipStream_t stream) {
    const float* prior = (const float*)d_in[0];
    const float* h     = (const float*)d_in[1];
    float* out = (float*)d_out;
    float* ws  = (float*)d_ws;

    float* bins = ws;                                         // 256 floats
    _Float16* P = (_Float16*)(ws + 16384);                    // 1,048,576 halves
    float* H2 = ws + 16384 + 524288;                          // 1024 floats
    _Float16* h16 = (_Float16*)(ws + 16384 + 524288 + 1024);  // 524,288 halves

    softmax_kernel<<<NB * NL, 256, 0, stream>>>(prior, h, P, H2, h16, bins);

    pair_kernel<<<PAIR_BLOCKS, 256, 0, stream>>>(P, H2, h16, bins);

    finalize_kernel<<<1, 256, 0, stream>>>(bins, out);
}

// Round 21
// 22.592 us; speedup vs baseline: 1.3763x; 1.2773x over previous
//
#include <hip/hip_runtime.h>
#include <math.h>

#define NB 16
#define NL 64
#define NK 32
#define NC 32
#define ND 512
#define EPSF 1e-10f

#define TILES_PER_B 36
#define PAIR_BLOCKS (NB * TILES_PER_B * 4)   // 2304 quarter-tile blocks

// att iff jsd < 5  <=>  stat = H2_i + H2_j + 64 - S < 10/ln2
#define THRS 14.426950408889634f
#define L2E  1.4426950408889634f

typedef _Float16 half2v __attribute__((ext_vector_type(2)));
typedef _Float16 half4v __attribute__((ext_vector_type(4)));
typedef _Float16 half8v __attribute__((ext_vector_type(8)));

// ws layout (floats):
//   partials : PAIR_BLOCKS*4 at float offset 0 (pad to 16384)
//   P  (f16) : 1,048,576 halves (2 MB) at float offset 16384
//   H2 (f32) : 1024 floats after P
//   h16(f16) : 524,288 halves (1 MB) after H2

__global__ void __launch_bounds__(256) softmax_kernel(
        const float* __restrict__ prior,
        const float* __restrict__ hg,
        _Float16* __restrict__ P,
        float* __restrict__ H2,
        _Float16* __restrict__ h16) {
    int bl = blockIdx.x;
    int t  = threadIdx.x;

    const float* src = prior + (size_t)bl * (NK * NC);
    float4 x = *(const float4*)(src + t * 4);
    float y0 = x.x * L2E, y1 = x.y * L2E, y2 = x.z * L2E, y3 = x.w * L2E;

    float m = fmaxf(fmaxf(y0, y1), fmaxf(y2, y3));
    #pragma unroll
    for (int w = 4; w >= 1; w >>= 1)
        m = fmaxf(m, __shfl_xor(m, w, 8));      // 8 lanes per k-row

    float e0 = exp2f(y0 - m), e1 = exp2f(y1 - m);
    float e2 = exp2f(y2 - m), e3 = exp2f(y3 - m);
    float s = e0 + e1 + e2 + e3;
    #pragma unroll
    for (int w = 4; w >= 1; w >>= 1)
        s += __shfl_xor(s, w, 8);

    float rs = 1.0f / s;
    float ls = __log2f(s);
    float p0 = e0 * rs, p1 = e1 * rs, p2 = e2 * rs, p3 = e3 * rs;
    float l0 = (y0 - m) - ls, l1 = (y1 - m) - ls;
    float l2 = (y2 - m) - ls, l3 = (y3 - m) - ls;

    half4v pv;
    pv[0] = (_Float16)fmaxf(p0, 1e-6f);
    pv[1] = (_Float16)fmaxf(p1, 1e-6f);
    pv[2] = (_Float16)fmaxf(p2, 1e-6f);
    pv[3] = (_Float16)fmaxf(p3, 1e-6f);
    *(half4v*)(P + (size_t)bl * (NK * NC) + t * 4) = pv;

    float2 hv = *(const float2*)(hg + (size_t)bl * ND + t * 2);
    half2v hh; hh[0] = (_Float16)hv.x; hh[1] = (_Float16)hv.y;
    *(half2v*)(h16 + (size_t)bl * ND + t * 2) = hh;

    float hacc = p0 * l0 + p1 * l1 + p2 * l2 + p3 * l3;
    #pragma unroll
    for (int w = 32; w >= 1; w >>= 1)
        hacc += __shfl_xor(hacc, w);
    __shared__ float red[4];
    int lane = t & 63, wib = t >> 6;
    if (lane == 0) red[wib] = hacc;
    __syncthreads();
    if (t == 0) H2[bl] = red[0] + red[1] + red[2] + red[3];
}

// DPP funnel add (row_shr:N, bound_ctrl) — reduce-to-LAST-lane of 16-row.
template<int CTRL>
__device__ __forceinline__ float dpp_add(float x) {
    int yi = __builtin_amdgcn_update_dpp(0, __float_as_int(x), CTRL, 0xF, 0xF, true);
    return x + __int_as_float(yi);
}

// 4-value reduce: value q's full sum lands on lane 16q+15.
__device__ __forceinline__ float bf4f(float v0, float v1, float v2, float v3,
                                      bool hi32, bool hi16) {
    float sel0 = hi32 ? v2 : v0, oth0 = hi32 ? v0 : v2;
    float sel1 = hi32 ? v3 : v1, oth1 = hi32 ? v1 : v3;
    float w0 = sel0 + __shfl_xor(oth0, 32);
    float w1 = sel1 + __shfl_xor(oth1, 32);
    float sel = hi16 ? w1 : w0, oth = hi16 ? w0 : w1;
    float x = sel + __shfl_xor(oth, 16);
    x = dpp_add<0x111>(x);   // row_shr:1
    x = dpp_add<0x112>(x);   // row_shr:2
    x = dpp_add<0x114>(x);   // row_shr:4
    x = dpp_add<0x118>(x);   // row_shr:8
    return x;                // full sum valid on lanes with (lane&15)==15
}

// 2304 blocks x 256 threads (4 waves). SINGLE CHANGE vs R17: XCD-bijective
// swizzle (2304 = 8*288; each XCD gets 288 consecutive quarter-tiles = 2
// whole batches -> per-XCD L2 working set ~400 KB instead of 3 MB).
// Hot loop identical to R17: one unconditional pass, pure ILP, plain
// partial stores, separate finalize.
__global__ void __launch_bounds__(256) pair_kernel(
        const _Float16* __restrict__ P,
        const float* __restrict__ H2g,
        const _Float16* __restrict__ h16,
        float* __restrict__ partials) {
    __shared__ float red[4][4];

    int tid  = threadIdx.x;
    int lane = tid & 63;
    int wv   = tid >> 6;

    // XCD-bijective swizzle: 2304 = 8 * 288
    int wg = (blockIdx.x & 7) * 288 + (blockIdx.x >> 3);

    int b      = wg / (TILES_PER_B * 4);
    int rem144 = wg % (TILES_PER_B * 4);
    int t36    = rem144 >> 2;
    int quad   = rem144 & 3;

    int ti = 0, rem = t36;
    while (rem >= 8 - ti) { rem -= 8 - ti; ++ti; }
    int tj = ti + rem;
    bool diag = (ti == tj);
    int bi0 = b * NL + ti * 8;
    int bj0 = b * NL + tj * 8;

    int r    = quad * 2 + (wv >> 1);     // row within tile, 0..7
    int scol = (wv & 1) * 4;             // column group: 0..3 or 4..7

    // i-row slice straight into registers (16 halves = 32B per lane)
    const _Float16* arow = P + (size_t)(bi0 + r) * (NK * NC) + lane * 16;
    half8v arA = *(const half8v*)(arow);
    half8v arB = *(const half8v*)(arow + 8);
    half8v hr  = *(const half8v*)(h16 + (size_t)(bi0 + r) * ND + lane * 8);
    float h2i = H2g[bi0 + r];

    const _Float16* Pj = P   + (size_t)bj0 * (NK * NC) + lane * 16;
    const _Float16* Hj = h16 + (size_t)bj0 * ND + lane * 8;

    bool hi32 = (lane & 32) != 0;
    bool hi16 = (lane & 16) != 0;
    int  sgrp = lane >> 4;               // 0..3
    bool actl = (lane & 15) == 15;       // funnel target lanes

    float S[4], M[4];
    #pragma unroll
    for (int q = 0; q < 4; ++q) {
        int s = scol + q;
        const _Float16* brow = Pj + s * 1024;
        half8v b0 = *(const half8v*)(brow);
        half8v b1 = *(const half8v*)(brow + 8);
        half8v t0 = arA + b0;
        half8v t1 = arB + b1;
        float a0 = 0.f, a1 = 0.f, a2 = 0.f, a3 = 0.f;
        #pragma unroll
        for (int e = 0; e < 8; e += 2) {
            float f0 = (float)t0[e];     a0 = fmaf(f0, __log2f(f0), a0);
            float f1 = (float)t0[e + 1]; a1 = fmaf(f1, __log2f(f1), a1);
            float g0 = (float)t1[e];     a2 = fmaf(g0, __log2f(g0), a2);
            float g1 = (float)t1[e + 1]; a3 = fmaf(g1, __log2f(g1), a3);
        }
        S[q] = (a0 + a1) + (a2 + a3);

        half8v hs = *(const half8v*)(Hj + s * 512);
        half8v d = hr - hs;
        float m0 = 0.f, m1 = 0.f;
        #pragma unroll
        for (int e = 0; e < 8; e += 2) {
            m0 = fmaf((float)d[e],     (float)d[e],     m0);
            m1 = fmaf((float)d[e + 1], (float)d[e + 1], m1);
        }
        M[q] = m0 + m1;
    }

    float xS = bf4f(S[0], S[1], S[2], S[3], hi32, hi16);
    float xM = bf4f(M[0], M[1], M[2], M[3], hi32, hi16);

    int s = scol + sgrp;
    float stat = h2i + H2g[bj0 + s] + 64.0f - xS;
    float mse  = xM * (1.0f / ND);
    float rt   = exp2f(-mse * L2E);
    bool valid = (!diag) || (s > r);
    bool isAtt = stat < THRS;

    float attN = (actl && valid && isAtt)  ? mse : 0.f;
    float attC = (actl && valid && isAtt)  ? 1.f : 0.f;
    float repN = (actl && valid && !isAtt) ? rt  : 0.f;
    float repC = (actl && valid && !isAtt) ? 1.f : 0.f;

    // combine the 4 act lanes (15,31,47,63)
    attN += __shfl_xor(attN, 16); attN += __shfl_xor(attN, 32);
    attC += __shfl_xor(attC, 16); attC += __shfl_xor(attC, 32);
    repN += __shfl_xor(repN, 16); repN += __shfl_xor(repN, 32);
    repC += __shfl_xor(repC, 16); repC += __shfl_xor(repC, 32);

    if (lane == 63) {
        red[wv][0] = attN; red[wv][1] = attC;
        red[wv][2] = repN; red[wv][3] = repC;
    }
    __syncthreads();
    if (tid < 4) {
        float v = red[0][tid] + red[1][tid] + red[2][tid] + red[3][tid];
        partials[blockIdx.x * 4 + tid] = v;
    }
}

__global__ void __launch_bounds__(256) finalize_kernel(
        const float* __restrict__ partials,
        float* __restrict__ out) {
    int tid = threadIdx.x;
    float a0 = 0.0f, a1 = 0.0f, a2 = 0.0f, a3 = 0.0f;
    for (int bkt = tid; bkt < PAIR_BLOCKS; bkt += 256) {
        a0 += partials[bkt * 4 + 0];
        a1 += partials[bkt * 4 + 1];
        a2 += partials[bkt * 4 + 2];
        a3 += partials[bkt * 4 + 3];
    }
    #pragma unroll
    for (int w = 32; w >= 1; w >>= 1) {
        a0 += __shfl_xor(a0, w);
        a1 += __shfl_xor(a1, w);
        a2 += __shfl_xor(a2, w);
        a3 += __shfl_xor(a3, w);
    }
    __shared__ float red[4][4];
    int lane = tid & 63, wib = tid >> 6;
    if (lane == 0) {
        red[wib][0] = a0; red[wib][1] = a1; red[wib][2] = a2; red[wib][3] = a3;
    }
    __syncthreads();
    if (tid == 0) {
        float s0 = red[0][0] + red[1][0] + red[2][0] + red[3][0];
        float s1 = red[0][1] + red[1][1] + red[2][1] + red[3][1];
        float s2 = red[0][2] + red[1][2] + red[2][2] + red[3][2];
        float s3 = red[0][3] + red[1][3] + red[2][3] + red[3][3];
        float la = s0 / (s1 + EPSF);
        float lr = s2 / (s3 + EPSF);
        out[0] = (la > 0.0f) ? la : 0.0f;
        out[1] = (lr > 0.0f) ? lr : 0.0f;
    }
}

extern "C" void kernel_launch(void* const* d_in, const int* in_sizes, int n_in,
                              void* d_out, int out_size, void* d_ws, size_t ws_size,
                              hipStream_t stream) {
    const float* prior = (const float*)d_in[0];
    const float* h     = (const float*)d_in[1];
    float* out = (float*)d_out;
    float* ws  = (float*)d_ws;

    float* partials = ws;                                     // 9216 floats
    _Float16* P = (_Float16*)(ws + 16384);                    // 1,048,576 halves
    float* H2 = ws + 16384 + 524288;                          // 1024 floats
    _Float16* h16 = (_Float16*)(ws + 16384 + 524288 + 1024);  // 524,288 halves

    softmax_kernel<<<NB * NL, 256, 0, stream>>>(prior, h, P, H2, h16);

    pair_kernel<<<PAIR_BLOCKS, 256, 0, stream>>>(P, H2, h16, partials);

    finalize_kernel<<<1, 256, 0, stream>>>(partials, out);
}

// Round 22
// 22.107 us; speedup vs baseline: 1.4065x; 1.0220x over previous
//
#include <hip/hip_runtime.h>
#include <math.h>

#define NB 16
#define NL 64
#define NK 32
#define NC 32
#define ND 512
#define EPSF 1e-10f

#define TILES_PER_B 36
#define PAIR_BLOCKS (NB * TILES_PER_B * 4)   // 2304 quarter-tile blocks

// att iff jsd < 5  <=>  stat = H2_i + H2_j + 64 - S < 10/ln2
#define THRS 14.426950408889634f
#define L2E  1.4426950408889634f

typedef _Float16 half2v __attribute__((ext_vector_type(2)));
typedef _Float16 half4v __attribute__((ext_vector_type(4)));
typedef _Float16 half8v __attribute__((ext_vector_type(8)));

// ws layout (floats):
//   partials : PAIR_BLOCKS*4 at float offset 0 (pad to 16384)
//   P  (f16) : 1,048,576 halves (2 MB) at float offset 16384
//   H2 (f32) : 1024 floats after P
//   h16(f16) : 524,288 halves (1 MB) after H2

// SINGLE CHANGE vs R20: XCD-affinity swizzle for softmax (1024 = 8*128) so
// XCD x computes/writes batches 2x,2x+1 -- the same batches pair-XCD x reads
// (producer-consumer L2 affinity across the dispatch boundary).
__global__ void __launch_bounds__(256) softmax_kernel(
        const float* __restrict__ prior,
        const float* __restrict__ hg,
        _Float16* __restrict__ P,
        float* __restrict__ H2,
        _Float16* __restrict__ h16) {
    int bl = (blockIdx.x & 7) * 128 + (blockIdx.x >> 3);
    int t  = threadIdx.x;

    const float* src = prior + (size_t)bl * (NK * NC);
    float4 x = *(const float4*)(src + t * 4);
    float y0 = x.x * L2E, y1 = x.y * L2E, y2 = x.z * L2E, y3 = x.w * L2E;

    float m = fmaxf(fmaxf(y0, y1), fmaxf(y2, y3));
    #pragma unroll
    for (int w = 4; w >= 1; w >>= 1)
        m = fmaxf(m, __shfl_xor(m, w, 8));      // 8 lanes per k-row

    float e0 = exp2f(y0 - m), e1 = exp2f(y1 - m);
    float e2 = exp2f(y2 - m), e3 = exp2f(y3 - m);
    float s = e0 + e1 + e2 + e3;
    #pragma unroll
    for (int w = 4; w >= 1; w >>= 1)
        s += __shfl_xor(s, w, 8);

    float rs = 1.0f / s;
    float ls = __log2f(s);
    float p0 = e0 * rs, p1 = e1 * rs, p2 = e2 * rs, p3 = e3 * rs;
    float l0 = (y0 - m) - ls, l1 = (y1 - m) - ls;
    float l2 = (y2 - m) - ls, l3 = (y3 - m) - ls;

    half4v pv;
    pv[0] = (_Float16)fmaxf(p0, 1e-6f);
    pv[1] = (_Float16)fmaxf(p1, 1e-6f);
    pv[2] = (_Float16)fmaxf(p2, 1e-6f);
    pv[3] = (_Float16)fmaxf(p3, 1e-6f);
    *(half4v*)(P + (size_t)bl * (NK * NC) + t * 4) = pv;

    float2 hv = *(const float2*)(hg + (size_t)bl * ND + t * 2);
    half2v hh; hh[0] = (_Float16)hv.x; hh[1] = (_Float16)hv.y;
    *(half2v*)(h16 + (size_t)bl * ND + t * 2) = hh;

    float hacc = p0 * l0 + p1 * l1 + p2 * l2 + p3 * l3;
    #pragma unroll
    for (int w = 32; w >= 1; w >>= 1)
        hacc += __shfl_xor(hacc, w);
    __shared__ float red[4];
    int lane = t & 63, wib = t >> 6;
    if (lane == 0) red[wib] = hacc;
    __syncthreads();
    if (t == 0) H2[bl] = red[0] + red[1] + red[2] + red[3];
}

// DPP funnel add (row_shr:N, bound_ctrl) — reduce-to-LAST-lane of 16-row.
template<int CTRL>
__device__ __forceinline__ float dpp_add(float x) {
    int yi = __builtin_amdgcn_update_dpp(0, __float_as_int(x), CTRL, 0xF, 0xF, true);
    return x + __int_as_float(yi);
}

// 4-value reduce: value q's full sum lands on lane 16q+15.
__device__ __forceinline__ float bf4f(float v0, float v1, float v2, float v3,
                                      bool hi32, bool hi16) {
    float sel0 = hi32 ? v2 : v0, oth0 = hi32 ? v0 : v2;
    float sel1 = hi32 ? v3 : v1, oth1 = hi32 ? v1 : v3;
    float w0 = sel0 + __shfl_xor(oth0, 32);
    float w1 = sel1 + __shfl_xor(oth1, 32);
    float sel = hi16 ? w1 : w0, oth = hi16 ? w0 : w1;
    float x = sel + __shfl_xor(oth, 16);
    x = dpp_add<0x111>(x);   // row_shr:1
    x = dpp_add<0x112>(x);   // row_shr:2
    x = dpp_add<0x114>(x);   // row_shr:4
    x = dpp_add<0x118>(x);   // row_shr:8
    return x;                // full sum valid on lanes with (lane&15)==15
}

// 2304 blocks x 256 threads (4 waves). XCD-bijective swizzle (R20). Hot loop
// identical to R17/R20: one unconditional pass, pure ILP, plain partial
// stores, separate finalize.
__global__ void __launch_bounds__(256) pair_kernel(
        const _Float16* __restrict__ P,
        const float* __restrict__ H2g,
        const _Float16* __restrict__ h16,
        float* __restrict__ partials) {
    __shared__ float red[4][4];

    int tid  = threadIdx.x;
    int lane = tid & 63;
    int wv   = tid >> 6;

    // XCD-bijective swizzle: 2304 = 8 * 288
    int wg = (blockIdx.x & 7) * 288 + (blockIdx.x >> 3);

    int b      = wg / (TILES_PER_B * 4);
    int rem144 = wg % (TILES_PER_B * 4);
    int t36    = rem144 >> 2;
    int quad   = rem144 & 3;

    int ti = 0, rem = t36;
    while (rem >= 8 - ti) { rem -= 8 - ti; ++ti; }
    int tj = ti + rem;
    bool diag = (ti == tj);
    int bi0 = b * NL + ti * 8;
    int bj0 = b * NL + tj * 8;

    int r    = quad * 2 + (wv >> 1);     // row within tile, 0..7
    int scol = (wv & 1) * 4;             // column group: 0..3 or 4..7

    // i-row slice straight into registers (16 halves = 32B per lane)
    const _Float16* arow = P + (size_t)(bi0 + r) * (NK * NC) + lane * 16;
    half8v arA = *(const half8v*)(arow);
    half8v arB = *(const half8v*)(arow + 8);
    half8v hr  = *(const half8v*)(h16 + (size_t)(bi0 + r) * ND + lane * 8);
    float h2i = H2g[bi0 + r];

    const _Float16* Pj = P   + (size_t)bj0 * (NK * NC) + lane * 16;
    const _Float16* Hj = h16 + (size_t)bj0 * ND + lane * 8;

    bool hi32 = (lane & 32) != 0;
    bool hi16 = (lane & 16) != 0;
    int  sgrp = lane >> 4;               // 0..3
    bool actl = (lane & 15) == 15;       // funnel target lanes

    float S[4], M[4];
    #pragma unroll
    for (int q = 0; q < 4; ++q) {
        int s = scol + q;
        const _Float16* brow = Pj + s * 1024;
        half8v b0 = *(const half8v*)(brow);
        half8v b1 = *(const half8v*)(brow + 8);
        half8v t0 = arA + b0;
        half8v t1 = arB + b1;
        float a0 = 0.f, a1 = 0.f, a2 = 0.f, a3 = 0.f;
        #pragma unroll
        for (int e = 0; e < 8; e += 2) {
            float f0 = (float)t0[e];     a0 = fmaf(f0, __log2f(f0), a0);
            float f1 = (float)t0[e + 1]; a1 = fmaf(f1, __log2f(f1), a1);
            float g0 = (float)t1[e];     a2 = fmaf(g0, __log2f(g0), a2);
            float g1 = (float)t1[e + 1]; a3 = fmaf(g1, __log2f(g1), a3);
        }
        S[q] = (a0 + a1) + (a2 + a3);

        half8v hs = *(const half8v*)(Hj + s * 512);
        half8v d = hr - hs;
        float m0 = 0.f, m1 = 0.f;
        #pragma unroll
        for (int e = 0; e < 8; e += 2) {
            m0 = fmaf((float)d[e],     (float)d[e],     m0);
            m1 = fmaf((float)d[e + 1], (float)d[e + 1], m1);
        }
        M[q] = m0 + m1;
    }

    float xS = bf4f(S[0], S[1], S[2], S[3], hi32, hi16);
    float xM = bf4f(M[0], M[1], M[2], M[3], hi32, hi16);

    int s = scol + sgrp;
    float stat = h2i + H2g[bj0 + s] + 64.0f - xS;
    float mse  = xM * (1.0f / ND);
    float rt   = exp2f(-mse * L2E);
    bool valid = (!diag) || (s > r);
    bool isAtt = stat < THRS;

    float attN = (actl && valid && isAtt)  ? mse : 0.f;
    float attC = (actl && valid && isAtt)  ? 1.f : 0.f;
    float repN = (actl && valid && !isAtt) ? rt  : 0.f;
    float repC = (actl && valid && !isAtt) ? 1.f : 0.f;

    // combine the 4 act lanes (15,31,47,63)
    attN += __shfl_xor(attN, 16); attN += __shfl_xor(attN, 32);
    attC += __shfl_xor(attC, 16); attC += __shfl_xor(attC, 32);
    repN += __shfl_xor(repN, 16); repN += __shfl_xor(repN, 32);
    repC += __shfl_xor(repC, 16); repC += __shfl_xor(repC, 32);

    if (lane == 63) {
        red[wv][0] = attN; red[wv][1] = attC;
        red[wv][2] = repN; red[wv][3] = repC;
    }
    __syncthreads();
    if (tid < 4) {
        float v = red[0][tid] + red[1][tid] + red[2][tid] + red[3][tid];
        partials[blockIdx.x * 4 + tid] = v;
    }
}

__global__ void __launch_bounds__(256) finalize_kernel(
        const float* __restrict__ partials,
        float* __restrict__ out) {
    int tid = threadIdx.x;
    float a0 = 0.0f, a1 = 0.0f, a2 = 0.0f, a3 = 0.0f;
    for (int bkt = tid; bkt < PAIR_BLOCKS; bkt += 256) {
        a0 += partials[bkt * 4 + 0];
        a1 += partials[bkt * 4 + 1];
        a2 += partials[bkt * 4 + 2];
        a3 += partials[bkt * 4 + 3];
    }
    #pragma unroll
    for (int w = 32; w >= 1; w >>= 1) {
        a0 += __shfl_xor(a0, w);
        a1 += __shfl_xor(a1, w);
        a2 += __shfl_xor(a2, w);
        a3 += __shfl_xor(a3, w);
    }
    __shared__ float red[4][4];
    int lane = tid & 63, wib = tid >> 6;
    if (lane == 0) {
        red[wib][0] = a0; red[wib][1] = a1; red[wib][2] = a2; red[wib][3] = a3;
    }
    __syncthreads();
    if (tid == 0) {
        float s0 = red[0][0] + red[1][0] + red[2][0] + red[3][0];
        float s1 = red[0][1] + red[1][1] + red[2][1] + red[3][1];
        float s2 = red[0][2] + red[1][2] + red[2][2] + red[3][2];
        float s3 = red[0][3] + red[1][3] + red[2][3] + red[3][3];
        float la = s0 / (s1 + EPSF);
        float lr = s2 / (s3 + EPSF);
        out[0] = (la > 0.0f) ? la : 0.0f;
        out[1] = (lr > 0.0f) ? lr : 0.0f;
    }
}

extern "C" void kernel_launch(void* const* d_in, const int* in_sizes, int n_in,
                              void* d_out, int out_size, void* d_ws, size_t ws_size,
                              hipStream_t stream) {
    const float* prior = (const float*)d_in[0];
    const float* h     = (const float*)d_in[1];
    float* out = (float*)d_out;
    float* ws  = (float*)d_ws;

    float* partials = ws;                                     // 9216 floats
    _Float16* P = (_Float16*)(ws + 16384);                    // 1,048,576 halves
    float* H2 = ws + 16384 + 524288;                          // 1024 floats
    _Float16* h16 = (_Float16*)(ws + 16384 + 524288 + 1024);  // 524,288 halves

    softmax_kernel<<<NB * NL, 256, 0, stream>>>(prior, h, P, H2, h16);

    pair_kernel<<<PAIR_BLOCKS, 256, 0, stream>>>(P, H2, h16, partials);

    finalize_kernel<<<1, 256, 0, stream>>>(partials, out);
}

// Round 23
// 21.714 us; speedup vs baseline: 1.4320x; 1.0181x over previous
//
#include <hip/hip_runtime.h>
#include <math.h>

#define NB 16
#define NL 64
#define NK 32
#define NC 32
#define ND 512
#define EPSF 1e-10f

#define TILES_PER_B 36
#define PAIR_BLOCKS (NB * TILES_PER_B * 4)   // 2304 quarter-tile blocks

// att iff jsd < 5  <=>  stat = H2_i + H2_j + 64 - S < 10/ln2
#define THRS 14.426950408889634f
#define L2E  1.4426950408889634f

typedef _Float16 half2v __attribute__((ext_vector_type(2)));
typedef _Float16 half4v __attribute__((ext_vector_type(4)));
typedef _Float16 half8v __attribute__((ext_vector_type(8)));

// ws layout (floats):
//   partials : PAIR_BLOCKS*4 at float offset 0 (pad to 16384)
//   P  (f16) : 1,048,576 halves (2 MB) at float offset 16384
//   H2 (f32) : 1024 floats after P
//   h16(f16) : 524,288 halves (1 MB) after H2

// XCD-affinity swizzle (R21): XCD x computes/writes batches 2x,2x+1 -- the
// same batches pair-XCD x reads (producer-consumer L2 affinity).
__global__ void __launch_bounds__(256) softmax_kernel(
        const float* __restrict__ prior,
        const float* __restrict__ hg,
        _Float16* __restrict__ P,
        float* __restrict__ H2,
        _Float16* __restrict__ h16) {
    int bl = (blockIdx.x & 7) * 128 + (blockIdx.x >> 3);
    int t  = threadIdx.x;

    const float* src = prior + (size_t)bl * (NK * NC);
    float4 x = *(const float4*)(src + t * 4);
    float y0 = x.x * L2E, y1 = x.y * L2E, y2 = x.z * L2E, y3 = x.w * L2E;

    float m = fmaxf(fmaxf(y0, y1), fmaxf(y2, y3));
    #pragma unroll
    for (int w = 4; w >= 1; w >>= 1)
        m = fmaxf(m, __shfl_xor(m, w, 8));      // 8 lanes per k-row

    float e0 = exp2f(y0 - m), e1 = exp2f(y1 - m);
    float e2 = exp2f(y2 - m), e3 = exp2f(y3 - m);
    float s = e0 + e1 + e2 + e3;
    #pragma unroll
    for (int w = 4; w >= 1; w >>= 1)
        s += __shfl_xor(s, w, 8);

    float rs = 1.0f / s;
    float ls = __log2f(s);
    float p0 = e0 * rs, p1 = e1 * rs, p2 = e2 * rs, p3 = e3 * rs;
    float l0 = (y0 - m) - ls, l1 = (y1 - m) - ls;
    float l2 = (y2 - m) - ls, l3 = (y3 - m) - ls;

    half4v pv;
    pv[0] = (_Float16)fmaxf(p0, 1e-6f);
    pv[1] = (_Float16)fmaxf(p1, 1e-6f);
    pv[2] = (_Float16)fmaxf(p2, 1e-6f);
    pv[3] = (_Float16)fmaxf(p3, 1e-6f);
    *(half4v*)(P + (size_t)bl * (NK * NC) + t * 4) = pv;

    float2 hv = *(const float2*)(hg + (size_t)bl * ND + t * 2);
    half2v hh; hh[0] = (_Float16)hv.x; hh[1] = (_Float16)hv.y;
    *(half2v*)(h16 + (size_t)bl * ND + t * 2) = hh;

    float hacc = p0 * l0 + p1 * l1 + p2 * l2 + p3 * l3;
    #pragma unroll
    for (int w = 32; w >= 1; w >>= 1)
        hacc += __shfl_xor(hacc, w);
    __shared__ float red[4];
    int lane = t & 63, wib = t >> 6;
    if (lane == 0) red[wib] = hacc;
    __syncthreads();
    if (t == 0) H2[bl] = red[0] + red[1] + red[2] + red[3];
}

// DPP funnel add (row_shr:N, bound_ctrl) — reduce-to-LAST-lane of 16-row.
template<int CTRL>
__device__ __forceinline__ float dpp_add(float x) {
    int yi = __builtin_amdgcn_update_dpp(0, __float_as_int(x), CTRL, 0xF, 0xF, true);
    return x + __int_as_float(yi);
}

// 4-value reduce: value q's full sum lands on lane 16q+15.
__device__ __forceinline__ float bf4f(float v0, float v1, float v2, float v3,
                                      bool hi32, bool hi16) {
    float sel0 = hi32 ? v2 : v0, oth0 = hi32 ? v0 : v2;
    float sel1 = hi32 ? v3 : v1, oth1 = hi32 ? v1 : v3;
    float w0 = sel0 + __shfl_xor(oth0, 32);
    float w1 = sel1 + __shfl_xor(oth1, 32);
    float sel = hi16 ? w1 : w0, oth = hi16 ? w0 : w1;
    float x = sel + __shfl_xor(oth, 16);
    x = dpp_add<0x111>(x);   // row_shr:1
    x = dpp_add<0x112>(x);   // row_shr:2
    x = dpp_add<0x114>(x);   // row_shr:4
    x = dpp_add<0x118>(x);   // row_shr:8
    return x;                // full sum valid on lanes with (lane&15)==15
}

// 2304 blocks x 256 threads (4 waves). XCD-bijective swizzle (R20). Hot loop
// identical to R17/R20/R21.
__global__ void __launch_bounds__(256) pair_kernel(
        const _Float16* __restrict__ P,
        const float* __restrict__ H2g,
        const _Float16* __restrict__ h16,
        float* __restrict__ partials) {
    __shared__ float red[4][4];

    int tid  = threadIdx.x;
    int lane = tid & 63;
    int wv   = tid >> 6;

    // XCD-bijective swizzle: 2304 = 8 * 288
    int wg = (blockIdx.x & 7) * 288 + (blockIdx.x >> 3);

    int b      = wg / (TILES_PER_B * 4);
    int rem144 = wg % (TILES_PER_B * 4);
    int t36    = rem144 >> 2;
    int quad   = rem144 & 3;

    int ti = 0, rem = t36;
    while (rem >= 8 - ti) { rem -= 8 - ti; ++ti; }
    int tj = ti + rem;
    bool diag = (ti == tj);
    int bi0 = b * NL + ti * 8;
    int bj0 = b * NL + tj * 8;

    int r    = quad * 2 + (wv >> 1);     // row within tile, 0..7
    int scol = (wv & 1) * 4;             // column group: 0..3 or 4..7

    // i-row slice straight into registers (16 halves = 32B per lane)
    const _Float16* arow = P + (size_t)(bi0 + r) * (NK * NC) + lane * 16;
    half8v arA = *(const half8v*)(arow);
    half8v arB = *(const half8v*)(arow + 8);
    half8v hr  = *(const half8v*)(h16 + (size_t)(bi0 + r) * ND + lane * 8);
    float h2i = H2g[bi0 + r];

    const _Float16* Pj = P   + (size_t)bj0 * (NK * NC) + lane * 16;
    const _Float16* Hj = h16 + (size_t)bj0 * ND + lane * 8;

    bool hi32 = (lane & 32) != 0;
    bool hi16 = (lane & 16) != 0;
    int  sgrp = lane >> 4;               // 0..3
    bool actl = (lane & 15) == 15;       // funnel target lanes

    float S[4], M[4];
    #pragma unroll
    for (int q = 0; q < 4; ++q) {
        int s = scol + q;
        const _Float16* brow = Pj + s * 1024;
        half8v b0 = *(const half8v*)(brow);
        half8v b1 = *(const half8v*)(brow + 8);
        half8v t0 = arA + b0;
        half8v t1 = arB + b1;
        float a0 = 0.f, a1 = 0.f, a2 = 0.f, a3 = 0.f;
        #pragma unroll
        for (int e = 0; e < 8; e += 2) {
            float f0 = (float)t0[e];     a0 = fmaf(f0, __log2f(f0), a0);
            float f1 = (float)t0[e + 1]; a1 = fmaf(f1, __log2f(f1), a1);
            float g0 = (float)t1[e];     a2 = fmaf(g0, __log2f(g0), a2);
            float g1 = (float)t1[e + 1]; a3 = fmaf(g1, __log2f(g1), a3);
        }
        S[q] = (a0 + a1) + (a2 + a3);

        half8v hs = *(const half8v*)(Hj + s * 512);
        half8v d = hr - hs;
        float m0 = 0.f, m1 = 0.f;
        #pragma unroll
        for (int e = 0; e < 8; e += 2) {
            m0 = fmaf((float)d[e],     (float)d[e],     m0);
            m1 = fmaf((float)d[e + 1], (float)d[e + 1], m1);
        }
        M[q] = m0 + m1;
    }

    float xS = bf4f(S[0], S[1], S[2], S[3], hi32, hi16);
    float xM = bf4f(M[0], M[1], M[2], M[3], hi32, hi16);

    int s = scol + sgrp;
    float stat = h2i + H2g[bj0 + s] + 64.0f - xS;
    float mse  = xM * (1.0f / ND);
    float rt   = exp2f(-mse * L2E);
    bool valid = (!diag) || (s > r);
    bool isAtt = stat < THRS;

    float attN = (actl && valid && isAtt)  ? mse : 0.f;
    float attC = (actl && valid && isAtt)  ? 1.f : 0.f;
    float repN = (actl && valid && !isAtt) ? rt  : 0.f;
    float repC = (actl && valid && !isAtt) ? 1.f : 0.f;

    // combine the 4 act lanes (15,31,47,63)
    attN += __shfl_xor(attN, 16); attN += __shfl_xor(attN, 32);
    attC += __shfl_xor(attC, 16); attC += __shfl_xor(attC, 32);
    repN += __shfl_xor(repN, 16); repN += __shfl_xor(repN, 32);
    repC += __shfl_xor(repC, 16); repC += __shfl_xor(repC, 32);

    if (lane == 63) {
        red[wv][0] = attN; red[wv][1] = attC;
        red[wv][2] = repN; red[wv][3] = repC;
    }
    __syncthreads();
    if (tid < 4) {
        float v = red[0][tid] + red[1][tid] + red[2][tid] + red[3][tid];
        partials[blockIdx.x * 4 + tid] = v;
    }
}

// SINGLE CHANGE vs R21: 1024 threads + float4 loads (2-3 coalesced vector
// loads per thread instead of 36 scalar loads), 16-wave reduce.
__global__ void __launch_bounds__(1024) finalize_kernel(
        const float4* __restrict__ partials4,
        float* __restrict__ out) {
    int tid  = threadIdx.x;
    int lane = tid & 63;
    int wv   = tid >> 6;          // 0..15

    float a0 = 0.f, a1 = 0.f, a2 = 0.f, a3 = 0.f;
    for (int i = tid; i < PAIR_BLOCKS; i += 1024) {
        float4 v = partials4[i];
        a0 += v.x; a1 += v.y; a2 += v.z; a3 += v.w;
    }
    #pragma unroll
    for (int w = 32; w >= 1; w >>= 1) {
        a0 += __shfl_xor(a0, w);
        a1 += __shfl_xor(a1, w);
        a2 += __shfl_xor(a2, w);
        a3 += __shfl_xor(a3, w);
    }
    __shared__ float red[16][4];
    if (lane == 0) {
        red[wv][0] = a0; red[wv][1] = a1;
        red[wv][2] = a2; red[wv][3] = a3;
    }
    __syncthreads();
    if (tid == 0) {
        float s0 = 0.f, s1 = 0.f, s2 = 0.f, s3 = 0.f;
        #pragma unroll
        for (int w = 0; w < 16; ++w) {
            s0 += red[w][0]; s1 += red[w][1];
            s2 += red[w][2]; s3 += red[w][3];
        }
        float la = s0 / (s1 + EPSF);
        float lr = s2 / (s3 + EPSF);
        out[0] = (la > 0.0f) ? la : 0.0f;
        out[1] = (lr > 0.0f) ? lr : 0.0f;
    }
}

extern "C" void kernel_launch(void* const* d_in, const int* in_sizes, int n_in,
                              void* d_out, int out_size, void* d_ws, size_t ws_size,
                              hipStream_t stream) {
    const float* prior = (const float*)d_in[0];
    const float* h     = (const float*)d_in[1];
    float* out = (float*)d_out;
    float* ws  = (float*)d_ws;

    float* partials = ws;                                     // 9216 floats
    _Float16* P = (_Float16*)(ws + 16384);                    // 1,048,576 halves
    float* H2 = ws + 16384 + 524288;                          // 1024 floats
    _Float16* h16 = (_Float16*)(ws + 16384 + 524288 + 1024);  // 524,288 halves

    softmax_kernel<<<NB * NL, 256, 0, stream>>>(prior, h, P, H2, h16);

    pair_kernel<<<PAIR_BLOCKS, 256, 0, stream>>>(P, H2, h16, partials);

    finalize_kernel<<<1, 1024, 0, stream>>>((const float4*)partials, out);
}

// Round 24
// 21.692 us; speedup vs baseline: 1.4334x; 1.0010x over previous
//
#include <hip/hip_runtime.h>
#include <math.h>

#define NB 16
#define NL 64
#define NK 32
#define NC 32
#define ND 512
#define EPSF 1e-10f

#define TILES_PER_B 36
#define PAIR_BLOCKS (NB * TILES_PER_B * 4)   // 2304 quarter-tile blocks

// att iff jsd < 5  <=>  stat = H2_i + H2_j + 64 - S < 10/ln2
#define THRS 14.426950408889634f
#define L2E  1.4426950408889634f

typedef _Float16 half2v __attribute__((ext_vector_type(2)));
typedef _Float16 half4v __attribute__((ext_vector_type(4)));
typedef _Float16 half8v __attribute__((ext_vector_type(8)));

// ws layout (floats):
//   partials : PAIR_BLOCKS*4 at float offset 0 (pad to 16384)
//   P  (f16) : 1,048,576 halves (2 MB) at float offset 16384
//   H2 (f32) : 1024 floats after P
//   h16(f16) : 524,288 halves (1 MB) after H2

// XCD-affinity swizzle (R21): XCD x computes/writes batches 2x,2x+1 -- the
// same batches pair-XCD x reads (producer-consumer L2 affinity).
__global__ void __launch_bounds__(256) softmax_kernel(
        const float* __restrict__ prior,
        const float* __restrict__ hg,
        _Float16* __restrict__ P,
        float* __restrict__ H2,
        _Float16* __restrict__ h16) {
    int bl = (blockIdx.x & 7) * 128 + (blockIdx.x >> 3);
    int t  = threadIdx.x;

    const float* src = prior + (size_t)bl * (NK * NC);
    float4 x = *(const float4*)(src + t * 4);
    float y0 = x.x * L2E, y1 = x.y * L2E, y2 = x.z * L2E, y3 = x.w * L2E;

    float m = fmaxf(fmaxf(y0, y1), fmaxf(y2, y3));
    #pragma unroll
    for (int w = 4; w >= 1; w >>= 1)
        m = fmaxf(m, __shfl_xor(m, w, 8));      // 8 lanes per k-row

    float e0 = exp2f(y0 - m), e1 = exp2f(y1 - m);
    float e2 = exp2f(y2 - m), e3 = exp2f(y3 - m);
    float s = e0 + e1 + e2 + e3;
    #pragma unroll
    for (int w = 4; w >= 1; w >>= 1)
        s += __shfl_xor(s, w, 8);

    float rs = 1.0f / s;
    float ls = __log2f(s);
    float p0 = e0 * rs, p1 = e1 * rs, p2 = e2 * rs, p3 = e3 * rs;
    float l0 = (y0 - m) - ls, l1 = (y1 - m) - ls;
    float l2 = (y2 - m) - ls, l3 = (y3 - m) - ls;

    half4v pv;
    pv[0] = (_Float16)fmaxf(p0, 1e-6f);
    pv[1] = (_Float16)fmaxf(p1, 1e-6f);
    pv[2] = (_Float16)fmaxf(p2, 1e-6f);
    pv[3] = (_Float16)fmaxf(p3, 1e-6f);
    *(half4v*)(P + (size_t)bl * (NK * NC) + t * 4) = pv;

    float2 hv = *(const float2*)(hg + (size_t)bl * ND + t * 2);
    half2v hh; hh[0] = (_Float16)hv.x; hh[1] = (_Float16)hv.y;
    *(half2v*)(h16 + (size_t)bl * ND + t * 2) = hh;

    float hacc = p0 * l0 + p1 * l1 + p2 * l2 + p3 * l3;
    #pragma unroll
    for (int w = 32; w >= 1; w >>= 1)
        hacc += __shfl_xor(hacc, w);
    __shared__ float red[4];
    int lane = t & 63, wib = t >> 6;
    if (lane == 0) red[wib] = hacc;
    __syncthreads();
    if (t == 0) H2[bl] = red[0] + red[1] + red[2] + red[3];
}

// DPP funnel add (row_shr:N, bound_ctrl) — reduce-to-LAST-lane of 16-row.
template<int CTRL>
__device__ __forceinline__ float dpp_add(float x) {
    int yi = __builtin_amdgcn_update_dpp(0, __float_as_int(x), CTRL, 0xF, 0xF, true);
    return x + __int_as_float(yi);
}

// 4-value reduce: value q's full sum lands on lane 16q+15.
__device__ __forceinline__ float bf4f(float v0, float v1, float v2, float v3,
                                      bool hi32, bool hi16) {
    float sel0 = hi32 ? v2 : v0, oth0 = hi32 ? v0 : v2;
    float sel1 = hi32 ? v3 : v1, oth1 = hi32 ? v1 : v3;
    float w0 = sel0 + __shfl_xor(oth0, 32);
    float w1 = sel1 + __shfl_xor(oth1, 32);
    float sel = hi16 ? w1 : w0, oth = hi16 ? w0 : w1;
    float x = sel + __shfl_xor(oth, 16);
    x = dpp_add<0x111>(x);   // row_shr:1
    x = dpp_add<0x112>(x);   // row_shr:2
    x = dpp_add<0x114>(x);   // row_shr:4
    x = dpp_add<0x118>(x);   // row_shr:8
    return x;                // full sum valid on lanes with (lane&15)==15
}

// 2304 blocks x 256 threads (4 waves). XCD-bijective swizzle (R20).
// SINGLE CHANGE vs R22: dense lane->element mapping. Lane owns halves
// [lane*8, +8) of the low 512 and [512+lane*8, +8) of the high 512, so each
// 16B load instruction covers a dense 1KB block (16 full cachelines) instead
// of a 2KB span at 50% density (32 half-used cachelines). The S-reduction is
// mapping-invariant.
__global__ void __launch_bounds__(256) pair_kernel(
        const _Float16* __restrict__ P,
        const float* __restrict__ H2g,
        const _Float16* __restrict__ h16,
        float* __restrict__ partials) {
    __shared__ float red[4][4];

    int tid  = threadIdx.x;
    int lane = tid & 63;
    int wv   = tid >> 6;

    // XCD-bijective swizzle: 2304 = 8 * 288
    int wg = (blockIdx.x & 7) * 288 + (blockIdx.x >> 3);

    int b      = wg / (TILES_PER_B * 4);
    int rem144 = wg % (TILES_PER_B * 4);
    int t36    = rem144 >> 2;
    int quad   = rem144 & 3;

    int ti = 0, rem = t36;
    while (rem >= 8 - ti) { rem -= 8 - ti; ++ti; }
    int tj = ti + rem;
    bool diag = (ti == tj);
    int bi0 = b * NL + ti * 8;
    int bj0 = b * NL + tj * 8;

    int r    = quad * 2 + (wv >> 1);     // row within tile, 0..7
    int scol = (wv & 1) * 4;             // column group: 0..3 or 4..7

    // i-row: dense halves [lane*8, +8) and [512+lane*8, +8)
    const _Float16* arow = P + (size_t)(bi0 + r) * (NK * NC);
    half8v arA = *(const half8v*)(arow + lane * 8);
    half8v arB = *(const half8v*)(arow + 512 + lane * 8);
    half8v hr  = *(const half8v*)(h16 + (size_t)(bi0 + r) * ND + lane * 8);
    float h2i = H2g[bi0 + r];

    const _Float16* Pj = P   + (size_t)bj0 * (NK * NC);
    const _Float16* Hj = h16 + (size_t)bj0 * ND + lane * 8;

    bool hi32 = (lane & 32) != 0;
    bool hi16 = (lane & 16) != 0;
    int  sgrp = lane >> 4;               // 0..3
    bool actl = (lane & 15) == 15;       // funnel target lanes

    float S[4], M[4];
    #pragma unroll
    for (int q = 0; q < 4; ++q) {
        int s = scol + q;
        const _Float16* brow = Pj + s * 1024;
        half8v b0 = *(const half8v*)(brow + lane * 8);
        half8v b1 = *(const half8v*)(brow + 512 + lane * 8);
        half8v t0 = arA + b0;
        half8v t1 = arB + b1;
        float a0 = 0.f, a1 = 0.f, a2 = 0.f, a3 = 0.f;
        #pragma unroll
        for (int e = 0; e < 8; e += 2) {
            float f0 = (float)t0[e];     a0 = fmaf(f0, __log2f(f0), a0);
            float f1 = (float)t0[e + 1]; a1 = fmaf(f1, __log2f(f1), a1);
            float g0 = (float)t1[e];     a2 = fmaf(g0, __log2f(g0), a2);
            float g1 = (float)t1[e + 1]; a3 = fmaf(g1, __log2f(g1), a3);
        }
        S[q] = (a0 + a1) + (a2 + a3);

        half8v hs = *(const half8v*)(Hj + s * 512);
        half8v d = hr - hs;
        float m0 = 0.f, m1 = 0.f;
        #pragma unroll
        for (int e = 0; e < 8; e += 2) {
            m0 = fmaf((float)d[e],     (float)d[e],     m0);
            m1 = fmaf((float)d[e + 1], (float)d[e + 1], m1);
        }
        M[q] = m0 + m1;
    }

    float xS = bf4f(S[0], S[1], S[2], S[3], hi32, hi16);
    float xM = bf4f(M[0], M[1], M[2], M[3], hi32, hi16);

    int s = scol + sgrp;
    float stat = h2i + H2g[bj0 + s] + 64.0f - xS;
    float mse  = xM * (1.0f / ND);
    float rt   = exp2f(-mse * L2E);
    bool valid = (!diag) || (s > r);
    bool isAtt = stat < THRS;

    float attN = (actl && valid && isAtt)  ? mse : 0.f;
    float attC = (actl && valid && isAtt)  ? 1.f : 0.f;
    float repN = (actl && valid && !isAtt) ? rt  : 0.f;
    float repC = (actl && valid && !isAtt) ? 1.f : 0.f;

    // combine the 4 act lanes (15,31,47,63)
    attN += __shfl_xor(attN, 16); attN += __shfl_xor(attN, 32);
    attC += __shfl_xor(attC, 16); attC += __shfl_xor(attC, 32);
    repN += __shfl_xor(repN, 16); repN += __shfl_xor(repN, 32);
    repC += __shfl_xor(repC, 16); repC += __shfl_xor(repC, 32);

    if (lane == 63) {
        red[wv][0] = attN; red[wv][1] = attC;
        red[wv][2] = repN; red[wv][3] = repC;
    }
    __syncthreads();
    if (tid < 4) {
        float v = red[0][tid] + red[1][tid] + red[2][tid] + red[3][tid];
        partials[blockIdx.x * 4 + tid] = v;
    }
}

// Wide finalize (R22): 1024 threads + float4 loads, 16-wave reduce.
__global__ void __launch_bounds__(1024) finalize_kernel(
        const float4* __restrict__ partials4,
        float* __restrict__ out) {
    int tid  = threadIdx.x;
    int lane = tid & 63;
    int wv   = tid >> 6;          // 0..15

    float a0 = 0.f, a1 = 0.f, a2 = 0.f, a3 = 0.f;
    for (int i = tid; i < PAIR_BLOCKS; i += 1024) {
        float4 v = partials4[i];
        a0 += v.x; a1 += v.y; a2 += v.z; a3 += v.w;
    }
    #pragma unroll
    for (int w = 32; w >= 1; w >>= 1) {
        a0 += __shfl_xor(a0, w);
        a1 += __shfl_xor(a1, w);
        a2 += __shfl_xor(a2, w);
        a3 += __shfl_xor(a3, w);
    }
    __shared__ float red[16][4];
    if (lane == 0) {
        red[wv][0] = a0; red[wv][1] = a1;
        red[wv][2] = a2; red[wv][3] = a3;
    }
    __syncthreads();
    if (tid == 0) {
        float s0 = 0.f, s1 = 0.f, s2 = 0.f, s3 = 0.f;
        #pragma unroll
        for (int w = 0; w < 16; ++w) {
            s0 += red[w][0]; s1 += red[w][1];
            s2 += red[w][2]; s3 += red[w][3];
        }
        float la = s0 / (s1 + EPSF);
        float lr = s2 / (s3 + EPSF);
        out[0] = (la > 0.0f) ? la : 0.0f;
        out[1] = (lr > 0.0f) ? lr : 0.0f;
    }
}

extern "C" void kernel_launch(void* const* d_in, const int* in_sizes, int n_in,
                              void* d_out, int out_size, void* d_ws, size_t ws_size,
                              hipStream_t stream) {
    const float* prior = (const float*)d_in[0];
    const float* h     = (const float*)d_in[1];
    float* out = (float*)d_out;
    float* ws  = (float*)d_ws;

    float* partials = ws;                                     // 9216 floats
    _Float16* P = (_Float16*)(ws + 16384);                    // 1,048,576 halves
    float* H2 = ws + 16384 + 524288;                          // 1024 floats
    _Float16* h16 = (_Float16*)(ws + 16384 + 524288 + 1024);  // 524,288 halves

    softmax_kernel<<<NB * NL, 256, 0, stream>>>(prior, h, P, H2, h16);

    pair_kernel<<<PAIR_BLOCKS, 256, 0, stream>>>(P, H2, h16, partials);

    finalize_kernel<<<1, 1024, 0, stream>>>((const float4*)partials, out);
}